// Round 4
// baseline (210.791 us; speedup 1.0000x reference)
//
#include <hip/hip_runtime.h>
#include <hip/hip_bf16.h>
#include <math.h>

// Problem constants
#define K_  32
#define HN  16      // n/2
#define N_  32
#define M_  128
#define B_  8
#define T_  2048
#define D_  128
#define BT  (B_*T_)     // 16384
#define KA  1056        // GEMM K: 1024 interleaved (Re,Im) + 32 xp
#define CHK 32          // chunks per series
#define CL  64          // chunk length (T/CHK)
#define NSER (B_*K_*HN) // 4096 series
#define NSC  (NSER*CHK) // 131072 series-chunks

typedef short short8 __attribute__((ext_vector_type(8)));
typedef float floatx4 __attribute__((ext_vector_type(4)));
typedef unsigned short ushort_t;
typedef unsigned int uint_t;

__device__ __forceinline__ ushort_t f2bf(float f) {
    __hip_bfloat16 h = __float2bfloat16(f);
    return *reinterpret_cast<ushort_t*>(&h);
}
__device__ __forceinline__ uint_t pack_bf2(float re, float im) {
    return ((uint_t)f2bf(im) << 16) | (uint_t)f2bf(re);
}

// ---------------------------------------------------------------------------
// K1: lambda (j<16) and Bp (j<16) via direct complex product.
// ws layout (floats): [0..512) lamRe, [512..1024) lamIm,
//                     [1024..1536) BpRe, [1536..2048) BpIm
// ---------------------------------------------------------------------------
__global__ void k_lambp(const float* __restrict__ theta, float* __restrict__ ws) {
    int tid = threadIdx.x;            // 512 threads: k*16 + j
    int k = tid >> 4, j = tid & 15;
    float angj = theta[k * HN + j];
    float pr = 1.f, pi = 0.f;
    for (int i = 0; i < N_; ++i) {
        if (i == j) continue;
        float angi = (i < HN) ? theta[k * HN + i] : -theta[k * HN + i - HN];
        float d = angi - angj;
        float tr = 1.f - cosf(d);
        float ti = -sinf(d);
        float nr = pr * tr - pi * ti;
        float ni = pr * ti + pi * tr;
        pr = nr; pi = ni;
    }
    float den = pr * pr + pi * pi;
    ws[tid]        = cosf(angj);
    ws[512 + tid]  = sinf(angj);
    ws[1024 + tid] = pr / den;
    ws[1536 + tid] = -pi / den;
}

// ---------------------------------------------------------------------------
// K2: build transposed bf16 weight matrix Wt [128 m][1056 c].
//  c = 2*(k*16+j)   : (ReCp[k,j,m] + ReCp[k,j+16,m]) / 32
//  c = 2*(k*16+j)+1 : (ImCp[k,j+16,m] - ImCp[k,j,m]) / 32
//  c = 1024 + k     : D[k,m] / 32
// ---------------------------------------------------------------------------
__global__ void k_weights(const float* __restrict__ lnC_r,
                          const float* __restrict__ lnC_i,
                          const float* __restrict__ D,
                          ushort_t* __restrict__ Wt) {
    int t = blockIdx.x * blockDim.x + threadIdx.x;
    const float inv = 1.f / 32.f;
    if (t < K_ * HN * M_) {                 // 65536
        int m = t & 127, j = (t >> 7) & 15, k = t >> 11;
        int i0 = (k * N_ + j) * M_ + m;
        int i1 = (k * N_ + j + HN) * M_ + m;
        float r0 = expf(lnC_r[i0]), c0 = cosf(lnC_i[i0]), s0 = sinf(lnC_i[i0]);
        float r1 = expf(lnC_r[i1]), c1 = cosf(lnC_i[i1]), s1 = sinf(lnC_i[i1]);
        float wr = (r0 * c0 + r1 * c1) * inv;
        float wi = (r1 * s1 - r0 * s0) * inv;
        *(uint_t*)(Wt + (size_t)m * KA + k * 32 + 2 * j) = pack_bf2(wr, wi);
    } else if (t < K_ * HN * M_ + K_ * M_) {
        int u = t - K_ * HN * M_;
        int m = u & 127, k = u >> 7;
        Wt[(size_t)m * KA + 1024 + k] = f2bf(D[k * M_ + m] * inv);
    }
}

// ---------------------------------------------------------------------------
// K3: xp[b,t,k] = sum_d x[b,t,d]*R[d,k]; bf16 scatter into A2 cols 1024..1055.
// ---------------------------------------------------------------------------
__global__ __launch_bounds__(256) void k_xp(const float* __restrict__ x,
                                            const float* __restrict__ R,
                                            float* __restrict__ xp,
                                            ushort_t* __restrict__ A2) {
    int kk = threadIdx.x & 31;
    int r8 = threadIdx.x >> 5;
    int row = blockIdx.x * 8 + r8;          // row = b*T + t
    const float* xr = x + (size_t)row * D_;
    float acc = 0.f;
    #pragma unroll 8
    for (int i = 0; i < D_; ++i) acc += xr[i] * R[i * K_ + kk];
    xp[row * K_ + kk] = acc;
    int b = row >> 11, tt = row & 2047;
    A2[(size_t)(tt * 8 + b) * KA + 1024 + kk] = f2bf(acc);
}

// ---------------------------------------------------------------------------
// K4a: per-chunk local end-state. Thread = (b,k,c,j); 131072 threads.
// ---------------------------------------------------------------------------
__global__ __launch_bounds__(256) void k_scan_ends(const float* __restrict__ xp,
                                                   const float* __restrict__ ws,
                                                   float* __restrict__ E) {
    int gid = blockIdx.x * 256 + threadIdx.x;
    int j = gid & 15, c = (gid >> 4) & 31, k = (gid >> 9) & 31, b = gid >> 14;
    int col = k * 16 + j;
    float lr = ws[col], li = ws[512 + col], br = ws[1024 + col], bi = ws[1536 + col];
    float sr = 0.f, si = 0.f;
    const float* xpb = xp + (size_t)b * T_ * K_ + k;
    int t0 = c * CL;
    for (int p = 0; p < CL; ++p) {
        int t = t0 + p;
        if (t > 0) {
            float xv = xpb[(t - 1) * K_];
            float nr = br * xv + lr * sr - li * si;
            float ni = bi * xv + lr * si + li * sr;
            sr = nr; si = ni;
        }
    }
    size_t eidx = ((size_t)(b * 32 + k) * 32 + c) * 16 + j;
    E[eidx] = sr;
    E[NSC + eidx] = si;
}

// ---------------------------------------------------------------------------
// K4b: exclusive-prefix carries per series.
// ---------------------------------------------------------------------------
__global__ void k_carries(const float* __restrict__ ws,
                          const float* __restrict__ E,
                          float* __restrict__ S) {
    int tid = blockIdx.x * blockDim.x + threadIdx.x;   // 4096
    int j = tid & 15, k = (tid >> 4) & 31, b = tid >> 9;
    int col = k * 16 + j;
    float lr = ws[col], li = ws[512 + col];
    float pr = lr, pi = li;                 // lambda^64 via 6 squarings
    #pragma unroll
    for (int q = 0; q < 6; ++q) {
        float nr = pr * pr - pi * pi;
        float ni = 2.f * pr * pi;
        pr = nr; pi = ni;
    }
    float sr = 0.f, si = 0.f;
    size_t base = (size_t)(b * 32 + k) * 32 * 16 + j;
    for (int c = 0; c < CHK; ++c) {
        size_t idx = base + (size_t)c * 16;
        S[idx] = sr;
        S[NSC + idx] = si;
        float er = E[idx], ei = E[NSC + idx];
        float nr = pr * sr - pi * si + er;
        float ni = pr * si + pi * sr + ei;
        sr = nr; si = ni;
    }
}

// ---------------------------------------------------------------------------
// K4c: final chunk scan seeded with carry; packed bf16 (Re,Im) stores to A2.
// Column pair (2c, 2c+1) = one uint32 at uint-index row*528 + c.
// ---------------------------------------------------------------------------
__global__ __launch_bounds__(256) void k_scan_write(const float* __restrict__ xp,
                                                    const float* __restrict__ ws,
                                                    const float* __restrict__ S,
                                                    uint_t* __restrict__ A2u) {
    int gid = blockIdx.x * 256 + threadIdx.x;
    int j = gid & 15, c = (gid >> 4) & 31, k = (gid >> 9) & 31, b = gid >> 14;
    int col = k * 16 + j;
    float lr = ws[col], li = ws[512 + col], br = ws[1024 + col], bi = ws[1536 + col];
    size_t sidx = ((size_t)(b * 32 + k) * 32 + c) * 16 + j;
    float sr = S[sidx], si = S[NSC + sidx];
    const float* xpb = xp + (size_t)b * T_ * K_ + k;
    int t0 = c * CL;
    uint_t* Ab = A2u + (size_t)(t0 * 8 + b) * (KA / 2) + col;
    for (int p = 0; p < CL; ++p) {
        int t = t0 + p;
        if (t > 0) {
            float xv = xpb[(t - 1) * K_];
            float nr = br * xv + lr * sr - li * si;
            float ni = bi * xv + lr * si + li * sr;
            sr = nr; si = ni;
        }
        Ab[0] = pack_bf2(sr, si);
        Ab += 8 * (KA / 2);
    }
}

// ---------------------------------------------------------------------------
// K5: bf16 MFMA GEMM. out[(b*T+t)*128+m] = sum_c A2[r=t*8+b][c]*Wt[m][c] + Do[m]
// 256 blocks x 256 thr (4 waves). Wave: 16 rows x 128 cols, K=1056 in 33 steps.
// MFMA 16x16x32: A-frag lane: A[row=lane&15][k=quad*8+i] (16B contiguous);
// B-frag lane: B[k=quad*8+i][col=lane&15] = Wt[col][k] (16B contiguous);
// D: col=lane&15, row=quad*4+reg.
// ---------------------------------------------------------------------------
__global__ __launch_bounds__(256) void k_gemm(const ushort_t* __restrict__ A2,
                                              const ushort_t* __restrict__ Wt,
                                              const float* __restrict__ Do,
                                              float* __restrict__ out) {
    int tid = threadIdx.x;
    int wave = tid >> 6;
    int lane = tid & 63;
    int l16 = lane & 15;
    int quad = lane >> 4;
    int row0 = blockIdx.x * 64 + wave * 16;

    const ushort_t* Ap = A2 + (size_t)(row0 + l16) * KA + quad * 8;
    const ushort_t* Wp = Wt + (size_t)l16 * KA + quad * 8;

    floatx4 acc[8];
    #pragma unroll
    for (int n = 0; n < 8; ++n) acc[n] = (floatx4){0.f, 0.f, 0.f, 0.f};

    for (int k0 = 0; k0 < KA; k0 += 32) {
        short8 av = *(const short8*)(Ap + k0);
        #pragma unroll
        for (int n = 0; n < 8; ++n) {
            short8 bv = *(const short8*)(Wp + (size_t)n * 16 * KA + k0);
            acc[n] = __builtin_amdgcn_mfma_f32_16x16x32_bf16(av, bv, acc[n], 0, 0, 0);
        }
    }

    #pragma unroll
    for (int n = 0; n < 8; ++n) {
        int col = n * 16 + l16;
        float dov = Do[col];
        #pragma unroll
        for (int q = 0; q < 4; ++q) {
            int r = row0 + quad * 4 + q;
            int b = r & 7, t = r >> 3;
            out[(size_t)(b * T_ + t) * M_ + col] = acc[n][q] + dov;
        }
    }
}

// ---------------------------------------------------------------------------
extern "C" void kernel_launch(void* const* d_in, const int* in_sizes, int n_in,
                              void* d_out, int out_size, void* d_ws, size_t ws_size,
                              hipStream_t stream) {
    const float* x     = (const float*)d_in[0];
    const float* R     = (const float*)d_in[1];
    const float* theta = (const float*)d_in[2];
    const float* lnC_r = (const float*)d_in[3];
    const float* lnC_i = (const float*)d_in[4];
    const float* D     = (const float*)d_in[5];
    const float* Do    = (const float*)d_in[6];
    float* out = (float*)d_out;

    float* wsf   = (float*)d_ws;
    float* lambp = wsf;                               // 2048 floats
    ushort_t* Wt = (ushort_t*)(wsf + 2048);           // 135168 ushorts = 67584 floats
    ushort_t* A2 = (ushort_t*)(wsf + 2048 + 67584);   // BT*KA ushorts = 8650752 floats
    float* xp    = wsf + 2048 + 67584 + 8650752;      // 524288 floats
    float* E     = xp + (size_t)BT * K_;              // 262144 floats (Re+Im)
    float* S     = E + 2 * (size_t)NSC;               // 262144 floats (Re+Im)

    k_lambp<<<1, 512, 0, stream>>>(theta, lambp);
    k_weights<<<272, 256, 0, stream>>>(lnC_r, lnC_i, D, Wt);
    k_xp<<<BT / 8, 256, 0, stream>>>(x, R, xp, A2);
    k_scan_ends<<<NSC / 256, 256, 0, stream>>>(xp, lambp, E);
    k_carries<<<16, 256, 0, stream>>>(lambp, E, S);
    k_scan_write<<<NSC / 256, 256, 0, stream>>>(xp, lambp, S, (uint_t*)A2);
    k_gemm<<<BT / 64, 256, 0, stream>>>(A2, Wt, Do, out);
}

// Round 5
// 156.929 us; speedup vs baseline: 1.3432x; 1.3432x over previous
//
#include <hip/hip_runtime.h>
#include <hip/hip_bf16.h>
#include <math.h>

// Problem constants
#define K_  32
#define HN  16      // n/2
#define N_  32
#define M_  128
#define B_  8
#define T_  2048
#define D_  128
#define BT  (B_*T_)     // 16384
#define KA  1056        // GEMM K: 1024 interleaved (Re,Im) + 32 xp
#define CHK 32          // chunks per series
#define CL  64          // chunk length (T/CHK)
#define NSER (B_*K_*HN) // 4096 series
#define NSC  (NSER*CHK) // 131072 series-chunks

typedef short short8 __attribute__((ext_vector_type(8)));
typedef float floatx4 __attribute__((ext_vector_type(4)));
typedef unsigned short ushort_t;
typedef unsigned int uint_t;

__device__ __forceinline__ ushort_t f2bf(float f) {
    __hip_bfloat16 h = __float2bfloat16(f);
    return *reinterpret_cast<ushort_t*>(&h);
}
__device__ __forceinline__ uint_t pack_bf2(float re, float im) {
    return ((uint_t)f2bf(im) << 16) | (uint_t)f2bf(re);
}

// ---------------------------------------------------------------------------
// K1: lambda (j<16) and Bp (j<16) via direct complex product.
// ws layout (floats): [0..512) lamRe, [512..1024) lamIm,
//                     [1024..1536) BpRe, [1536..2048) BpIm
// ---------------------------------------------------------------------------
__global__ void k_lambp(const float* __restrict__ theta, float* __restrict__ ws) {
    int tid = threadIdx.x;            // 512 threads: k*16 + j
    int k = tid >> 4, j = tid & 15;
    float angj = theta[k * HN + j];
    float pr = 1.f, pi = 0.f;
    for (int i = 0; i < N_; ++i) {
        if (i == j) continue;
        float angi = (i < HN) ? theta[k * HN + i] : -theta[k * HN + i - HN];
        float d = angi - angj;
        float tr = 1.f - cosf(d);
        float ti = -sinf(d);
        float nr = pr * tr - pi * ti;
        float ni = pr * ti + pi * tr;
        pr = nr; pi = ni;
    }
    float den = pr * pr + pi * pi;
    ws[tid]        = cosf(angj);
    ws[512 + tid]  = sinf(angj);
    ws[1024 + tid] = pr / den;
    ws[1536 + tid] = -pi / den;
}

// ---------------------------------------------------------------------------
// K2: build transposed bf16 weight matrix Wt [128 m][1056 c].
// ---------------------------------------------------------------------------
__global__ void k_weights(const float* __restrict__ lnC_r,
                          const float* __restrict__ lnC_i,
                          const float* __restrict__ D,
                          ushort_t* __restrict__ Wt) {
    int t = blockIdx.x * blockDim.x + threadIdx.x;
    const float inv = 1.f / 32.f;
    if (t < K_ * HN * M_) {                 // 65536
        int m = t & 127, j = (t >> 7) & 15, k = t >> 11;
        int i0 = (k * N_ + j) * M_ + m;
        int i1 = (k * N_ + j + HN) * M_ + m;
        float r0 = expf(lnC_r[i0]), c0 = cosf(lnC_i[i0]), s0 = sinf(lnC_i[i0]);
        float r1 = expf(lnC_r[i1]), c1 = cosf(lnC_i[i1]), s1 = sinf(lnC_i[i1]);
        float wr = (r0 * c0 + r1 * c1) * inv;
        float wi = (r1 * s1 - r0 * s0) * inv;
        *(uint_t*)(Wt + (size_t)m * KA + k * 32 + 2 * j) = pack_bf2(wr, wi);
    } else if (t < K_ * HN * M_ + K_ * M_) {
        int u = t - K_ * HN * M_;
        int m = u & 127, k = u >> 7;
        Wt[(size_t)m * KA + 1024 + k] = f2bf(D[k * M_ + m] * inv);
    }
}

// ---------------------------------------------------------------------------
// K3: xp[b,t,k] = sum_d x[b,t,d]*R[d,k]; bf16 scatter into A2 cols 1024..1055.
// ---------------------------------------------------------------------------
__global__ __launch_bounds__(256) void k_xp(const float* __restrict__ x,
                                            const float* __restrict__ R,
                                            float* __restrict__ xp,
                                            ushort_t* __restrict__ A2) {
    int kk = threadIdx.x & 31;
    int r8 = threadIdx.x >> 5;
    int row = blockIdx.x * 8 + r8;          // row = b*T + t
    const float* xr = x + (size_t)row * D_;
    float acc = 0.f;
    #pragma unroll 8
    for (int i = 0; i < D_; ++i) acc += xr[i] * R[i * K_ + kk];
    xp[row * K_ + kk] = acc;
    int b = row >> 11, tt = row & 2047;
    A2[(size_t)(tt * 8 + b) * KA + 1024 + kk] = f2bf(acc);
}

// ---------------------------------------------------------------------------
// K4a: per-chunk local end-state. Thread = (b,k,c,j); 131072 threads.
// ---------------------------------------------------------------------------
__global__ __launch_bounds__(256) void k_scan_ends(const float* __restrict__ xp,
                                                   const float* __restrict__ ws,
                                                   float* __restrict__ E) {
    int gid = blockIdx.x * 256 + threadIdx.x;
    int j = gid & 15, c = (gid >> 4) & 31, k = (gid >> 9) & 31, b = gid >> 14;
    int col = k * 16 + j;
    float lr = ws[col], li = ws[512 + col], br = ws[1024 + col], bi = ws[1536 + col];
    float sr = 0.f, si = 0.f;
    const float* xpb = xp + (size_t)b * T_ * K_ + k;
    int t0 = c * CL;
    for (int p = 0; p < CL; ++p) {
        int t = t0 + p;
        if (t > 0) {
            float xv = xpb[(t - 1) * K_];
            float nr = br * xv + lr * sr - li * si;
            float ni = bi * xv + lr * si + li * sr;
            sr = nr; si = ni;
        }
    }
    size_t eidx = ((size_t)(b * 32 + k) * 32 + c) * 16 + j;
    E[eidx] = sr;
    E[NSC + eidx] = si;
}

// ---------------------------------------------------------------------------
// K4b: exclusive-prefix carries per series.
// ---------------------------------------------------------------------------
__global__ void k_carries(const float* __restrict__ ws,
                          const float* __restrict__ E,
                          float* __restrict__ S) {
    int tid = blockIdx.x * blockDim.x + threadIdx.x;   // 4096
    int j = tid & 15, k = (tid >> 4) & 31, b = tid >> 9;
    int col = k * 16 + j;
    float lr = ws[col], li = ws[512 + col];
    float pr = lr, pi = li;                 // lambda^64 via 6 squarings
    #pragma unroll
    for (int q = 0; q < 6; ++q) {
        float nr = pr * pr - pi * pi;
        float ni = 2.f * pr * pi;
        pr = nr; pi = ni;
    }
    float sr = 0.f, si = 0.f;
    size_t base = (size_t)(b * 32 + k) * 32 * 16 + j;
    for (int c = 0; c < CHK; ++c) {
        size_t idx = base + (size_t)c * 16;
        S[idx] = sr;
        S[NSC + idx] = si;
        float er = E[idx], ei = E[NSC + idx];
        float nr = pr * sr - pi * si + er;
        float ni = pr * si + pi * sr + ei;
        sr = nr; si = ni;
    }
}

// ---------------------------------------------------------------------------
// K4c: final chunk scan seeded with carry; packed bf16 (Re,Im) stores to A2.
// ---------------------------------------------------------------------------
__global__ __launch_bounds__(256) void k_scan_write(const float* __restrict__ xp,
                                                    const float* __restrict__ ws,
                                                    const float* __restrict__ S,
                                                    uint_t* __restrict__ A2u) {
    int gid = blockIdx.x * 256 + threadIdx.x;
    int j = gid & 15, c = (gid >> 4) & 31, k = (gid >> 9) & 31, b = gid >> 14;
    int col = k * 16 + j;
    float lr = ws[col], li = ws[512 + col], br = ws[1024 + col], bi = ws[1536 + col];
    size_t sidx = ((size_t)(b * 32 + k) * 32 + c) * 16 + j;
    float sr = S[sidx], si = S[NSC + sidx];
    const float* xpb = xp + (size_t)b * T_ * K_ + k;
    int t0 = c * CL;
    uint_t* Ab = A2u + (size_t)(t0 * 8 + b) * (KA / 2) + col;
    for (int p = 0; p < CL; ++p) {
        int t = t0 + p;
        if (t > 0) {
            float xv = xpb[(t - 1) * K_];
            float nr = br * xv + lr * sr - li * si;
            float ni = bi * xv + lr * si + li * sr;
            sr = nr; si = ni;
        }
        Ab[0] = pack_bf2(sr, si);
        Ab += 8 * (KA / 2);
    }
}

// ---------------------------------------------------------------------------
// K5: bf16 MFMA GEMM, latency-optimized.
// Grid 1024 blocks x 256 thr; block = 16 rows, wave w = cols w*32..w*32+31.
// Per wave: 2 accumulators (n=0,1), K-loop 11 groups x 3 steps x 32.
// 9 independent 16B loads per group -> 6 MFMAs. 4 blocks/CU = 16 waves/CU.
// ---------------------------------------------------------------------------
__global__ __launch_bounds__(256, 4) void k_gemm(const ushort_t* __restrict__ A2,
                                                 const ushort_t* __restrict__ Wt,
                                                 const float* __restrict__ Do,
                                                 float* __restrict__ out) {
    int tid = threadIdx.x;
    int wave = tid >> 6;                 // col-group 0..3
    int lane = tid & 63;
    int l16 = lane & 15;
    int quad = lane >> 4;
    int row0 = blockIdx.x * 16;

    const ushort_t* Ap = A2 + (size_t)(row0 + l16) * KA + quad * 8;
    const ushort_t* W0 = Wt + (size_t)(wave * 32 + l16) * KA + quad * 8;
    const ushort_t* W1 = W0 + (size_t)16 * KA;

    floatx4 acc0 = (floatx4){0.f, 0.f, 0.f, 0.f};
    floatx4 acc1 = (floatx4){0.f, 0.f, 0.f, 0.f};

    for (int g = 0; g < 11; ++g) {
        int k0 = g * 96;
        short8 a0  = *(const short8*)(Ap + k0);
        short8 a1  = *(const short8*)(Ap + k0 + 32);
        short8 a2  = *(const short8*)(Ap + k0 + 64);
        short8 b00 = *(const short8*)(W0 + k0);
        short8 b01 = *(const short8*)(W1 + k0);
        short8 b10 = *(const short8*)(W0 + k0 + 32);
        short8 b11 = *(const short8*)(W1 + k0 + 32);
        short8 b20 = *(const short8*)(W0 + k0 + 64);
        short8 b21 = *(const short8*)(W1 + k0 + 64);
        acc0 = __builtin_amdgcn_mfma_f32_16x16x32_bf16(a0, b00, acc0, 0, 0, 0);
        acc1 = __builtin_amdgcn_mfma_f32_16x16x32_bf16(a0, b01, acc1, 0, 0, 0);
        acc0 = __builtin_amdgcn_mfma_f32_16x16x32_bf16(a1, b10, acc0, 0, 0, 0);
        acc1 = __builtin_amdgcn_mfma_f32_16x16x32_bf16(a1, b11, acc1, 0, 0, 0);
        acc0 = __builtin_amdgcn_mfma_f32_16x16x32_bf16(a2, b20, acc0, 0, 0, 0);
        acc1 = __builtin_amdgcn_mfma_f32_16x16x32_bf16(a2, b21, acc1, 0, 0, 0);
    }

    #pragma unroll
    for (int n = 0; n < 2; ++n) {
        int col = wave * 32 + n * 16 + l16;
        float dov = Do[col];
        floatx4 a = n ? acc1 : acc0;
        #pragma unroll
        for (int q = 0; q < 4; ++q) {
            int r = row0 + quad * 4 + q;
            int b = r & 7, t = r >> 3;
            out[(size_t)(b * T_ + t) * M_ + col] = a[q] + dov;
        }
    }
}

// ---------------------------------------------------------------------------
extern "C" void kernel_launch(void* const* d_in, const int* in_sizes, int n_in,
                              void* d_out, int out_size, void* d_ws, size_t ws_size,
                              hipStream_t stream) {
    const float* x     = (const float*)d_in[0];
    const float* R     = (const float*)d_in[1];
    const float* theta = (const float*)d_in[2];
    const float* lnC_r = (const float*)d_in[3];
    const float* lnC_i = (const float*)d_in[4];
    const float* D     = (const float*)d_in[5];
    const float* Do    = (const float*)d_in[6];
    float* out = (float*)d_out;

    float* wsf   = (float*)d_ws;
    float* lambp = wsf;                               // 2048 floats
    ushort_t* Wt = (ushort_t*)(wsf + 2048);           // 135168 ushorts = 67584 floats
    ushort_t* A2 = (ushort_t*)(wsf + 2048 + 67584);   // BT*KA ushorts = 8650752 floats
    float* xp    = wsf + 2048 + 67584 + 8650752;      // 524288 floats
    float* E     = xp + (size_t)BT * K_;              // 262144 floats (Re+Im)
    float* S     = E + 2 * (size_t)NSC;               // 262144 floats (Re+Im)

    k_lambp<<<1, 512, 0, stream>>>(theta, lambp);
    k_weights<<<272, 256, 0, stream>>>(lnC_r, lnC_i, D, Wt);
    k_xp<<<BT / 8, 256, 0, stream>>>(x, R, xp, A2);
    k_scan_ends<<<NSC / 256, 256, 0, stream>>>(xp, lambp, E);
    k_carries<<<16, 256, 0, stream>>>(lambp, E, S);
    k_scan_write<<<NSC / 256, 256, 0, stream>>>(xp, lambp, S, (uint_t*)A2);
    k_gemm<<<BT / 16, 256, 0, stream>>>(A2, Wt, Do, out);
}

// Round 10
// 144.725 us; speedup vs baseline: 1.4565x; 1.0843x over previous
//
#include <hip/hip_runtime.h>
#include <hip/hip_bf16.h>
#include <math.h>

// Problem constants
#define K_  32
#define HN  16      // n/2
#define N_  32
#define M_  128
#define B_  8
#define T_  2048
#define D_  128
#define BT  (B_*T_)     // 16384
#define KA  1056        // GEMM K: 1024 interleaved (Re,Im) + 32 xp
#define CHK 32          // chunks per series
#define CL  64          // chunk length (T/CHK)
#define NSER (B_*K_*HN) // 4096 series
#define NSC  (NSER*CHK) // 131072 series-chunks

typedef short short8 __attribute__((ext_vector_type(8)));
typedef float floatx4 __attribute__((ext_vector_type(4)));
typedef unsigned short ushort_t;
typedef unsigned int uint_t;

__device__ __forceinline__ ushort_t f2bf(float f) {
    __hip_bfloat16 h = __float2bfloat16(f);
    return *reinterpret_cast<ushort_t*>(&h);
}
__device__ __forceinline__ uint_t pack_bf2(float re, float im) {
    return ((uint_t)f2bf(im) << 16) | (uint_t)f2bf(re);
}

// ---------------------------------------------------------------------------
// K1: lambda (j<16) and Bp (j<16) via direct complex product.
// ws layout (floats): [0..512) lamRe, [512..1024) lamIm,
//                     [1024..1536) BpRe, [1536..2048) BpIm
// ---------------------------------------------------------------------------
__global__ void k_lambp(const float* __restrict__ theta, float* __restrict__ ws) {
    int tid = threadIdx.x;            // 512 threads: k*16 + j
    int k = tid >> 4, j = tid & 15;
    float angj = theta[k * HN + j];
    float pr = 1.f, pi = 0.f;
    for (int i = 0; i < N_; ++i) {
        if (i == j) continue;
        float angi = (i < HN) ? theta[k * HN + i] : -theta[k * HN + i - HN];
        float d = angi - angj;
        float tr = 1.f - cosf(d);
        float ti = -sinf(d);
        float nr = pr * tr - pi * ti;
        float ni = pr * ti + pi * tr;
        pr = nr; pi = ni;
    }
    float den = pr * pr + pi * pi;
    ws[tid]        = cosf(angj);
    ws[512 + tid]  = sinf(angj);
    ws[1024 + tid] = pr / den;
    ws[1536 + tid] = -pi / den;
}

// ---------------------------------------------------------------------------
// K2: build transposed bf16 weight matrix Wt [128 m][1056 c].  (R5-identical)
// ---------------------------------------------------------------------------
__global__ void k_weights(const float* __restrict__ lnC_r,
                          const float* __restrict__ lnC_i,
                          const float* __restrict__ D,
                          ushort_t* __restrict__ Wt) {
    int t = blockIdx.x * blockDim.x + threadIdx.x;
    const float inv = 1.f / 32.f;
    if (t < K_ * HN * M_) {                 // 65536
        int m = t & 127, j = (t >> 7) & 15, k = t >> 11;
        int i0 = (k * N_ + j) * M_ + m;
        int i1 = (k * N_ + j + HN) * M_ + m;
        float r0 = expf(lnC_r[i0]), c0 = cosf(lnC_i[i0]), s0 = sinf(lnC_i[i0]);
        float r1 = expf(lnC_r[i1]), c1 = cosf(lnC_i[i1]), s1 = sinf(lnC_i[i1]);
        float wr = (r0 * c0 + r1 * c1) * inv;
        float wi = (r1 * s1 - r0 * s0) * inv;
        *(uint_t*)(Wt + (size_t)m * KA + k * 32 + 2 * j) = pack_bf2(wr, wi);
    } else if (t < K_ * HN * M_ + K_ * M_) {
        int u = t - K_ * HN * M_;
        int m = u & 127, k = u >> 7;
        Wt[(size_t)m * KA + 1024 + k] = f2bf(D[k * M_ + m] * inv);
    }
}

// ---------------------------------------------------------------------------
// K3: xp projection. Writes (a) bf16 scatter into A2 cols 1024..1055 (as R5),
// (b) time-transposed SHIFTED copy xpT[b][k][t] = xp[b][t-1][k], xpT[..][0]=0
// (explicit zero — ws is poisoned 0xAA). Scans then read contiguous floats.
// ---------------------------------------------------------------------------
__global__ __launch_bounds__(256) void k_xp(const float* __restrict__ x,
                                            const float* __restrict__ R,
                                            float* __restrict__ xpT,
                                            ushort_t* __restrict__ A2) {
    int kk = threadIdx.x & 31;
    int r8 = threadIdx.x >> 5;
    int row = blockIdx.x * 8 + r8;          // row = b*T + t
    const float* xr = x + (size_t)row * D_;
    float acc = 0.f;
    #pragma unroll 8
    for (int i = 0; i < D_; ++i) acc += xr[i] * R[i * K_ + kk];
    int b = row >> 11, tt = row & 2047;
    A2[(size_t)(tt * 8 + b) * KA + 1024 + kk] = f2bf(acc);
    size_t base = (size_t)(b * K_ + kk) * T_;
    if (tt < T_ - 1) xpT[base + tt + 1] = acc;
    if (tt == 0)     xpT[base] = 0.f;
}

// ---------------------------------------------------------------------------
// K4a: per-chunk local end-state. Thread = (b,k,c,j); branchless float4 scan.
// s_p = lam*s_{p-1} + Bp*xpT[t0+p]  (xpT pre-shifted; p=0 of chunk 0 gives 0)
// ---------------------------------------------------------------------------
__global__ __launch_bounds__(256) void k_scan_ends(const float* __restrict__ xpT,
                                                   const float* __restrict__ ws,
                                                   float* __restrict__ E) {
    int gid = blockIdx.x * 256 + threadIdx.x;
    int j = gid & 15, c = (gid >> 4) & 31, k = (gid >> 9) & 31, b = gid >> 14;
    int col = k * 16 + j;
    float lr = ws[col], li = ws[512 + col], br = ws[1024 + col], bi = ws[1536 + col];
    float sr = 0.f, si = 0.f;
    const float4* xv4 = (const float4*)(xpT + (size_t)(b * K_ + k) * T_ + c * CL);
    for (int u = 0; u < CL / 4; ++u) {
        float4 xv = xv4[u];
        #pragma unroll
        for (int v = 0; v < 4; ++v) {
            float x1 = (v == 0) ? xv.x : (v == 1) ? xv.y : (v == 2) ? xv.z : xv.w;
            float nr = br * x1 + lr * sr - li * si;
            float ni = bi * x1 + lr * si + li * sr;
            sr = nr; si = ni;
        }
    }
    size_t eidx = ((size_t)(b * 32 + k) * 32 + c) * 16 + j;
    E[eidx] = sr;
    E[NSC + eidx] = si;
}

// ---------------------------------------------------------------------------
// K4b: exclusive-prefix carries per series.  (R5-identical)
// ---------------------------------------------------------------------------
__global__ void k_carries(const float* __restrict__ ws,
                          const float* __restrict__ E,
                          float* __restrict__ S) {
    int tid = blockIdx.x * blockDim.x + threadIdx.x;   // 4096
    int j = tid & 15, k = (tid >> 4) & 31, b = tid >> 9;
    int col = k * 16 + j;
    float lr = ws[col], li = ws[512 + col];
    float pr = lr, pi = li;                 // lambda^64 via 6 squarings
    #pragma unroll
    for (int q = 0; q < 6; ++q) {
        float nr = pr * pr - pi * pi;
        float ni = 2.f * pr * pi;
        pr = nr; pi = ni;
    }
    float sr = 0.f, si = 0.f;
    size_t base = (size_t)(b * 32 + k) * 32 * 16 + j;
    for (int c = 0; c < CHK; ++c) {
        size_t idx = base + (size_t)c * 16;
        S[idx] = sr;
        S[NSC + idx] = si;
        float er = E[idx], ei = E[NSC + idx];
        float nr = pr * sr - pi * si + er;
        float ni = pr * si + pi * sr + ei;
        sr = nr; si = ni;
    }
}

// ---------------------------------------------------------------------------
// K4c: seeded chunk scan, branchless float4; packed bf16 stores to A2 (as R5).
// ---------------------------------------------------------------------------
__global__ __launch_bounds__(256) void k_scan_write(const float* __restrict__ xpT,
                                                    const float* __restrict__ ws,
                                                    const float* __restrict__ S,
                                                    uint_t* __restrict__ A2u) {
    int gid = blockIdx.x * 256 + threadIdx.x;
    int j = gid & 15, c = (gid >> 4) & 31, k = (gid >> 9) & 31, b = gid >> 14;
    int col = k * 16 + j;
    float lr = ws[col], li = ws[512 + col], br = ws[1024 + col], bi = ws[1536 + col];
    size_t sidx = ((size_t)(b * 32 + k) * 32 + c) * 16 + j;
    float sr = S[sidx], si = S[NSC + sidx];
    int t0 = c * CL;
    const float4* xv4 = (const float4*)(xpT + (size_t)(b * K_ + k) * T_ + t0);
    uint_t* Ab = A2u + (size_t)(t0 * 8 + b) * (KA / 2) + col;
    for (int u = 0; u < CL / 4; ++u) {
        float4 xv = xv4[u];
        #pragma unroll
        for (int v = 0; v < 4; ++v) {
            float x1 = (v == 0) ? xv.x : (v == 1) ? xv.y : (v == 2) ? xv.z : xv.w;
            float nr = br * x1 + lr * sr - li * si;
            float ni = bi * x1 + lr * si + li * sr;
            sr = nr; si = ni;
            Ab[0] = pack_bf2(sr, si);
            Ab += 8 * (KA / 2);
        }
    }
}

// ---------------------------------------------------------------------------
// K5: bf16 MFMA GEMM — EXACT R5 copy (validated).
// Grid 1024 blocks x 256 thr; block = 16 rows, wave w = cols w*32..w*32+31.
// ---------------------------------------------------------------------------
__global__ __launch_bounds__(256, 4) void k_gemm(const ushort_t* __restrict__ A2,
                                                 const ushort_t* __restrict__ Wt,
                                                 const float* __restrict__ Do,
                                                 float* __restrict__ out) {
    int tid = threadIdx.x;
    int wave = tid >> 6;                 // col-group 0..3
    int lane = tid & 63;
    int l16 = lane & 15;
    int quad = lane >> 4;
    int row0 = blockIdx.x * 16;

    const ushort_t* Ap = A2 + (size_t)(row0 + l16) * KA + quad * 8;
    const ushort_t* W0 = Wt + (size_t)(wave * 32 + l16) * KA + quad * 8;
    const ushort_t* W1 = W0 + (size_t)16 * KA;

    floatx4 acc0 = (floatx4){0.f, 0.f, 0.f, 0.f};
    floatx4 acc1 = (floatx4){0.f, 0.f, 0.f, 0.f};

    for (int g = 0; g < 11; ++g) {
        int k0 = g * 96;
        short8 a0  = *(const short8*)(Ap + k0);
        short8 a1  = *(const short8*)(Ap + k0 + 32);
        short8 a2  = *(const short8*)(Ap + k0 + 64);
        short8 b00 = *(const short8*)(W0 + k0);
        short8 b01 = *(const short8*)(W1 + k0);
        short8 b10 = *(const short8*)(W0 + k0 + 32);
        short8 b11 = *(const short8*)(W1 + k0 + 32);
        short8 b20 = *(const short8*)(W0 + k0 + 64);
        short8 b21 = *(const short8*)(W1 + k0 + 64);
        acc0 = __builtin_amdgcn_mfma_f32_16x16x32_bf16(a0, b00, acc0, 0, 0, 0);
        acc1 = __builtin_amdgcn_mfma_f32_16x16x32_bf16(a0, b01, acc1, 0, 0, 0);
        acc0 = __builtin_amdgcn_mfma_f32_16x16x32_bf16(a1, b10, acc0, 0, 0, 0);
        acc1 = __builtin_amdgcn_mfma_f32_16x16x32_bf16(a1, b11, acc1, 0, 0, 0);
        acc0 = __builtin_amdgcn_mfma_f32_16x16x32_bf16(a2, b20, acc0, 0, 0, 0);
        acc1 = __builtin_amdgcn_mfma_f32_16x16x32_bf16(a2, b21, acc1, 0, 0, 0);
    }

    #pragma unroll
    for (int n = 0; n < 2; ++n) {
        int col = wave * 32 + n * 16 + l16;
        float dov = Do[col];
        floatx4 a = n ? acc1 : acc0;
        #pragma unroll
        for (int q = 0; q < 4; ++q) {
            int r = row0 + quad * 4 + q;
            int b = r & 7, t = r >> 3;
            out[(size_t)(b * T_ + t) * M_ + col] = a[q] + dov;
        }
    }
}

// ---------------------------------------------------------------------------
extern "C" void kernel_launch(void* const* d_in, const int* in_sizes, int n_in,
                              void* d_out, int out_size, void* d_ws, size_t ws_size,
                              hipStream_t stream) {
    const float* x     = (const float*)d_in[0];
    const float* R     = (const float*)d_in[1];
    const float* theta = (const float*)d_in[2];
    const float* lnC_r = (const float*)d_in[3];
    const float* lnC_i = (const float*)d_in[4];
    const float* D     = (const float*)d_in[5];
    const float* Do    = (const float*)d_in[6];
    float* out = (float*)d_out;

    float* wsf   = (float*)d_ws;
    float* lambp = wsf;                               // 2048 floats
    ushort_t* Wt = (ushort_t*)(wsf + 2048);           // 135168 ushorts = 67584 floats
    ushort_t* A2 = (ushort_t*)(wsf + 2048 + 67584);   // BT*KA ushorts = 8650752 floats
    float* xpT   = wsf + 2048 + 67584 + 8650752;      // 524288 floats
    float* E     = xpT + (size_t)BT * K_;             // 262144 floats (Re+Im)
    float* S     = E + 2 * (size_t)NSC;               // 262144 floats (Re+Im)

    k_lambp<<<1, 512, 0, stream>>>(theta, lambp);
    k_weights<<<272, 256, 0, stream>>>(lnC_r, lnC_i, D, Wt);
    k_xp<<<BT / 8, 256, 0, stream>>>(x, R, xpT, A2);
    k_scan_ends<<<NSC / 256, 256, 0, stream>>>(xpT, lambp, E);
    k_carries<<<16, 256, 0, stream>>>(lambp, E, S);
    k_scan_write<<<NSC / 256, 256, 0, stream>>>(xpT, lambp, S, (uint_t*)A2);
    k_gemm<<<BT / 16, 256, 0, stream>>>(A2, Wt, Do, out);
}

// Round 11
// 132.591 us; speedup vs baseline: 1.5898x; 1.0915x over previous
//
#include <hip/hip_runtime.h>
#include <hip/hip_bf16.h>
#include <math.h>

// Problem constants
#define K_  32
#define HN  16      // n/2
#define N_  32
#define M_  128
#define B_  8
#define T_  2048
#define D_  128
#define BT  (B_*T_)     // 16384
#define KA  1056        // GEMM K: 1024 interleaved (Re,Im) + 32 xp
#define CHK 32          // chunks per series
#define CL  64          // chunk length (T/CHK)
#define NSER (B_*K_*HN) // 4096 series
#define NSC  (NSER*CHK) // 131072 series-chunks

typedef short short8 __attribute__((ext_vector_type(8)));
typedef float floatx4 __attribute__((ext_vector_type(4)));
typedef unsigned short ushort_t;
typedef unsigned int uint_t;

__device__ __forceinline__ ushort_t f2bf(float f) {
    __hip_bfloat16 h = __float2bfloat16(f);
    return *reinterpret_cast<ushort_t*>(&h);
}
__device__ __forceinline__ uint_t pack_bf2(float re, float im) {
    return ((uint_t)f2bf(im) << 16) | (uint_t)f2bf(re);
}

// ---------------------------------------------------------------------------
// K_PRE: fused independent preprocessing, partitioned by blockIdx.
//   block 0        : lambda/Bp table (512 work items, 2 per thread)
//   blocks 1..272  : Wt build (bf16, transposed, interleaved Re/Im)
//   blocks 273..784: xp projection -> xpT (shifted, time-major) + A2 cols
//                    1024..1055. 32 rows/block, x staged in LDS, 4 rows/thread.
// All three parts are input-only readers writing disjoint buffers.
// ---------------------------------------------------------------------------
__global__ __launch_bounds__(256) void k_pre(const float* __restrict__ theta,
                                             const float* __restrict__ lnC_r,
                                             const float* __restrict__ lnC_i,
                                             const float* __restrict__ D,
                                             const float* __restrict__ x,
                                             const float* __restrict__ R,
                                             float* __restrict__ ws,
                                             ushort_t* __restrict__ Wt,
                                             float* __restrict__ xpT,
                                             ushort_t* __restrict__ A2) {
    __shared__ float xls[32 * 128];
    int bid = blockIdx.x, tid = threadIdx.x;
    if (bid == 0) {
        // ---- lambda & Bp ----
        #pragma unroll
        for (int rep = 0; rep < 2; ++rep) {
            int t2 = rep * 256 + tid;          // k*16 + j
            int k = t2 >> 4, j = t2 & 15;
            float angj = theta[k * HN + j];
            float pr = 1.f, pi = 0.f;
            for (int i = 0; i < N_; ++i) {
                if (i == j) continue;
                float angi = (i < HN) ? theta[k * HN + i] : -theta[k * HN + i - HN];
                float d = angi - angj;
                float tr = 1.f - cosf(d);
                float ti = -sinf(d);
                float nr = pr * tr - pi * ti;
                float ni = pr * ti + pi * tr;
                pr = nr; pi = ni;
            }
            float den = pr * pr + pi * pi;
            ws[t2]        = cosf(angj);
            ws[512 + t2]  = sinf(angj);
            ws[1024 + t2] = pr / den;
            ws[1536 + t2] = -pi / den;
        }
    } else if (bid <= 272) {
        // ---- Wt build ----
        int t = (bid - 1) * 256 + tid;
        const float inv = 1.f / 32.f;
        if (t < K_ * HN * M_) {                 // 65536
            int m = t & 127, j = (t >> 7) & 15, k = t >> 11;
            int i0 = (k * N_ + j) * M_ + m;
            int i1 = (k * N_ + j + HN) * M_ + m;
            float r0 = expf(lnC_r[i0]), c0 = cosf(lnC_i[i0]), s0 = sinf(lnC_i[i0]);
            float r1 = expf(lnC_r[i1]), c1 = cosf(lnC_i[i1]), s1 = sinf(lnC_i[i1]);
            float wr = (r0 * c0 + r1 * c1) * inv;
            float wi = (r1 * s1 - r0 * s0) * inv;
            *(uint_t*)(Wt + (size_t)m * KA + k * 32 + 2 * j) = pack_bf2(wr, wi);
        } else if (t < K_ * HN * M_ + K_ * M_) {
            int u = t - K_ * HN * M_;
            int m = u & 127, k = u >> 7;
            Wt[(size_t)m * KA + 1024 + k] = f2bf(D[k * M_ + m] * inv);
        }
    } else {
        // ---- xp projection ----
        int xb = bid - 273;                     // 0..511
        int b = xb >> 6;
        int tbase = (xb & 63) * 32;
        const float4* xsrc = (const float4*)(x + ((size_t)b * T_ + tbase) * D_);
        float4* xd = (float4*)xls;
        #pragma unroll
        for (int e = 0; e < 4; ++e) xd[tid + 256 * e] = xsrc[tid + 256 * e];
        __syncthreads();
        int kk = tid & 31, rg = tid >> 5;       // rg 0..7
        float accv[4] = {0.f, 0.f, 0.f, 0.f};
        #pragma unroll 4
        for (int i = 0; i < D_; ++i) {
            float rv = R[i * K_ + kk];
            #pragma unroll
            for (int rr = 0; rr < 4; ++rr)
                accv[rr] += xls[(rg + 8 * rr) * D_ + i] * rv;
        }
        #pragma unroll
        for (int rr = 0; rr < 4; ++rr) {
            int tt = tbase + rg + 8 * rr;
            A2[(size_t)(tt * 8 + b) * KA + 1024 + kk] = f2bf(accv[rr]);
            size_t base = (size_t)(b * K_ + kk) * T_;
            if (tt < T_ - 1) xpT[base + tt + 1] = accv[rr];
            if (tt == 0)     xpT[base] = 0.f;
        }
    }
}

// ---------------------------------------------------------------------------
// K4a: per-chunk local end-state. Thread = (b,k,c,j); branchless float4 scan.
// ---------------------------------------------------------------------------
__global__ __launch_bounds__(256) void k_scan_ends(const float* __restrict__ xpT,
                                                   const float* __restrict__ ws,
                                                   float* __restrict__ E) {
    int gid = blockIdx.x * 256 + threadIdx.x;
    int j = gid & 15, c = (gid >> 4) & 31, k = (gid >> 9) & 31, b = gid >> 14;
    int col = k * 16 + j;
    float lr = ws[col], li = ws[512 + col], br = ws[1024 + col], bi = ws[1536 + col];
    float sr = 0.f, si = 0.f;
    const float4* xv4 = (const float4*)(xpT + (size_t)(b * K_ + k) * T_ + c * CL);
    for (int u = 0; u < CL / 4; ++u) {
        float4 xv = xv4[u];
        #pragma unroll
        for (int v = 0; v < 4; ++v) {
            float x1 = (v == 0) ? xv.x : (v == 1) ? xv.y : (v == 2) ? xv.z : xv.w;
            float nr = br * x1 + lr * sr - li * si;
            float ni = bi * x1 + lr * si + li * sr;
            sr = nr; si = ni;
        }
    }
    size_t eidx = ((size_t)(b * 32 + k) * 32 + c) * 16 + j;
    E[eidx] = sr;
    E[NSC + eidx] = si;
}

// ---------------------------------------------------------------------------
// K4b: exclusive-prefix carries per series.
// ---------------------------------------------------------------------------
__global__ void k_carries(const float* __restrict__ ws,
                          const float* __restrict__ E,
                          float* __restrict__ S) {
    int tid = blockIdx.x * blockDim.x + threadIdx.x;   // 4096
    int j = tid & 15, k = (tid >> 4) & 31, b = tid >> 9;
    int col = k * 16 + j;
    float lr = ws[col], li = ws[512 + col];
    float pr = lr, pi = li;                 // lambda^64 via 6 squarings
    #pragma unroll
    for (int q = 0; q < 6; ++q) {
        float nr = pr * pr - pi * pi;
        float ni = 2.f * pr * pi;
        pr = nr; pi = ni;
    }
    float sr = 0.f, si = 0.f;
    size_t base = (size_t)(b * 32 + k) * 32 * 16 + j;
    for (int c = 0; c < CHK; ++c) {
        size_t idx = base + (size_t)c * 16;
        S[idx] = sr;
        S[NSC + idx] = si;
        float er = E[idx], ei = E[NSC + idx];
        float nr = pr * sr - pi * si + er;
        float ni = pr * si + pi * sr + ei;
        sr = nr; si = ni;
    }
}

// ---------------------------------------------------------------------------
// K4c: seeded chunk scan, branchless float4; packed bf16 stores to A2.
// ---------------------------------------------------------------------------
__global__ __launch_bounds__(256) void k_scan_write(const float* __restrict__ xpT,
                                                    const float* __restrict__ ws,
                                                    const float* __restrict__ S,
                                                    uint_t* __restrict__ A2u) {
    int gid = blockIdx.x * 256 + threadIdx.x;
    int j = gid & 15, c = (gid >> 4) & 31, k = (gid >> 9) & 31, b = gid >> 14;
    int col = k * 16 + j;
    float lr = ws[col], li = ws[512 + col], br = ws[1024 + col], bi = ws[1536 + col];
    size_t sidx = ((size_t)(b * 32 + k) * 32 + c) * 16 + j;
    float sr = S[sidx], si = S[NSC + sidx];
    int t0 = c * CL;
    const float4* xv4 = (const float4*)(xpT + (size_t)(b * K_ + k) * T_ + t0);
    uint_t* Ab = A2u + (size_t)(t0 * 8 + b) * (KA / 2) + col;
    for (int u = 0; u < CL / 4; ++u) {
        float4 xv = xv4[u];
        #pragma unroll
        for (int v = 0; v < 4; ++v) {
            float x1 = (v == 0) ? xv.x : (v == 1) ? xv.y : (v == 2) ? xv.z : xv.w;
            float nr = br * x1 + lr * sr - li * si;
            float ni = bi * x1 + lr * si + li * sr;
            sr = nr; si = ni;
            Ab[0] = pack_bf2(sr, si);
            Ab += 8 * (KA / 2);
        }
    }
}

// ---------------------------------------------------------------------------
// K5: bf16 MFMA GEMM, re-blocked. 512 blocks x 256 thr; block = 32 rows x
// 128 cols. Wave: rh = wave&1 (rows rh*16..+15), chh = wave>>1 (cols
// chh*64..+63), 4 accs. K in 11 groups of 96: 3 A-loads + 12 B-loads ->
// 12 MFMAs. B L2 traffic halved vs R5 (each block reads Wt once: 138 MB).
// Same K-accumulation order as R5 -> bit-identical results.
// ---------------------------------------------------------------------------
__global__ __launch_bounds__(256, 2) void k_gemm(const ushort_t* __restrict__ A2,
                                                 const ushort_t* __restrict__ Wt,
                                                 const float* __restrict__ Do,
                                                 float* __restrict__ out) {
    int tid = threadIdx.x;
    int wave = tid >> 6;
    int rh = wave & 1;
    int chh = wave >> 1;
    int lane = tid & 63;
    int l16 = lane & 15;
    int quad = lane >> 4;
    int row0 = blockIdx.x * 32 + rh * 16;

    const ushort_t* Ap = A2 + (size_t)(row0 + l16) * KA + quad * 8;
    const ushort_t* Wp = Wt + (size_t)(chh * 64 + l16) * KA + quad * 8;

    floatx4 acc[4];
    #pragma unroll
    for (int n = 0; n < 4; ++n) acc[n] = (floatx4){0.f, 0.f, 0.f, 0.f};

    for (int g = 0; g < 11; ++g) {
        int k0 = g * 96;
        short8 a0 = *(const short8*)(Ap + k0);
        short8 a1 = *(const short8*)(Ap + k0 + 32);
        short8 a2 = *(const short8*)(Ap + k0 + 64);
        short8 bv[4][3];
        #pragma unroll
        for (int n = 0; n < 4; ++n) {
            #pragma unroll
            for (int s = 0; s < 3; ++s)
                bv[n][s] = *(const short8*)(Wp + (size_t)n * 16 * KA + k0 + s * 32);
        }
        #pragma unroll
        for (int n = 0; n < 4; ++n)
            acc[n] = __builtin_amdgcn_mfma_f32_16x16x32_bf16(a0, bv[n][0], acc[n], 0, 0, 0);
        #pragma unroll
        for (int n = 0; n < 4; ++n)
            acc[n] = __builtin_amdgcn_mfma_f32_16x16x32_bf16(a1, bv[n][1], acc[n], 0, 0, 0);
        #pragma unroll
        for (int n = 0; n < 4; ++n)
            acc[n] = __builtin_amdgcn_mfma_f32_16x16x32_bf16(a2, bv[n][2], acc[n], 0, 0, 0);
    }

    #pragma unroll
    for (int n = 0; n < 4; ++n) {
        int col = chh * 64 + n * 16 + l16;
        float dov = Do[col];
        #pragma unroll
        for (int q = 0; q < 4; ++q) {
            int r = row0 + quad * 4 + q;
            int b = r & 7, t = r >> 3;
            out[(size_t)(b * T_ + t) * M_ + col] = acc[n][q] + dov;
        }
    }
}

// ---------------------------------------------------------------------------
extern "C" void kernel_launch(void* const* d_in, const int* in_sizes, int n_in,
                              void* d_out, int out_size, void* d_ws, size_t ws_size,
                              hipStream_t stream) {
    const float* x     = (const float*)d_in[0];
    const float* R     = (const float*)d_in[1];
    const float* theta = (const float*)d_in[2];
    const float* lnC_r = (const float*)d_in[3];
    const float* lnC_i = (const float*)d_in[4];
    const float* D     = (const float*)d_in[5];
    const float* Do    = (const float*)d_in[6];
    float* out = (float*)d_out;

    float* wsf   = (float*)d_ws;
    float* lambp = wsf;                               // 2048 floats
    ushort_t* Wt = (ushort_t*)(wsf + 2048);           // 135168 ushorts = 67584 floats
    ushort_t* A2 = (ushort_t*)(wsf + 2048 + 67584);   // BT*KA ushorts = 8650752 floats
    float* xpT   = wsf + 2048 + 67584 + 8650752;      // 524288 floats
    float* E     = xpT + (size_t)BT * K_;             // 262144 floats (Re+Im)
    float* S     = E + 2 * (size_t)NSC;               // 262144 floats (Re+Im)

    k_pre<<<785, 256, 0, stream>>>(theta, lnC_r, lnC_i, D, x, R,
                                   lambp, Wt, xpT, A2);
    k_scan_ends<<<NSC / 256, 256, 0, stream>>>(xpT, lambp, E);
    k_carries<<<16, 256, 0, stream>>>(lambp, E, S);
    k_scan_write<<<NSC / 256, 256, 0, stream>>>(xpT, lambp, S, (uint_t*)A2);
    k_gemm<<<512, 256, 0, stream>>>(A2, Wt, Do, out);
}

// Round 12
// 127.092 us; speedup vs baseline: 1.6586x; 1.0433x over previous
//
#include <hip/hip_runtime.h>
#include <hip/hip_bf16.h>
#include <math.h>

// Problem constants
#define K_  32
#define HN  16      // n/2
#define N_  32
#define M_  128
#define B_  8
#define T_  2048
#define D_  128
#define BT  (B_*T_)     // 16384
#define KA  1056        // GEMM K: 1024 interleaved (Re,Im) + 32 xp
#define CHK 32          // chunks per series
#define CL  64          // chunk length (T/CHK)

typedef short short8 __attribute__((ext_vector_type(8)));
typedef float floatx4 __attribute__((ext_vector_type(4)));
typedef unsigned short ushort_t;
typedef unsigned int uint_t;

__device__ __forceinline__ ushort_t f2bf(float f) {
    __hip_bfloat16 h = __float2bfloat16(f);
    return *reinterpret_cast<ushort_t*>(&h);
}
__device__ __forceinline__ uint_t pack_bf2(float re, float im) {
    return ((uint_t)f2bf(im) << 16) | (uint_t)f2bf(re);
}

// ---------------------------------------------------------------------------
// K_PRE: fused independent preprocessing, partitioned by blockIdx (as R11).
//   block 0        : lambda/Bp table
//   blocks 1..272  : Wt build (bf16, transposed, interleaved Re/Im)
//   blocks 273..784: xp projection -> xpT (shifted, time-major) + A2 cols
//                    1024..1055. 32 rows/block, x staged in LDS.
// ---------------------------------------------------------------------------
__global__ __launch_bounds__(256) void k_pre(const float* __restrict__ theta,
                                             const float* __restrict__ lnC_r,
                                             const float* __restrict__ lnC_i,
                                             const float* __restrict__ D,
                                             const float* __restrict__ x,
                                             const float* __restrict__ R,
                                             float* __restrict__ ws,
                                             ushort_t* __restrict__ Wt,
                                             float* __restrict__ xpT,
                                             ushort_t* __restrict__ A2) {
    __shared__ float xls[32 * 128];
    int bid = blockIdx.x, tid = threadIdx.x;
    if (bid == 0) {
        // ---- lambda & Bp ----
        #pragma unroll
        for (int rep = 0; rep < 2; ++rep) {
            int t2 = rep * 256 + tid;          // k*16 + j
            int k = t2 >> 4, j = t2 & 15;
            float angj = theta[k * HN + j];
            float pr = 1.f, pi = 0.f;
            for (int i = 0; i < N_; ++i) {
                if (i == j) continue;
                float angi = (i < HN) ? theta[k * HN + i] : -theta[k * HN + i - HN];
                float d = angi - angj;
                float tr = 1.f - cosf(d);
                float ti = -sinf(d);
                float nr = pr * tr - pi * ti;
                float ni = pr * ti + pi * tr;
                pr = nr; pi = ni;
            }
            float den = pr * pr + pi * pi;
            ws[t2]        = cosf(angj);
            ws[512 + t2]  = sinf(angj);
            ws[1024 + t2] = pr / den;
            ws[1536 + t2] = -pi / den;
        }
    } else if (bid <= 272) {
        // ---- Wt build ----
        int t = (bid - 1) * 256 + tid;
        const float inv = 1.f / 32.f;
        if (t < K_ * HN * M_) {                 // 65536
            int m = t & 127, j = (t >> 7) & 15, k = t >> 11;
            int i0 = (k * N_ + j) * M_ + m;
            int i1 = (k * N_ + j + HN) * M_ + m;
            float r0 = expf(lnC_r[i0]), c0 = cosf(lnC_i[i0]), s0 = sinf(lnC_i[i0]);
            float r1 = expf(lnC_r[i1]), c1 = cosf(lnC_i[i1]), s1 = sinf(lnC_i[i1]);
            float wr = (r0 * c0 + r1 * c1) * inv;
            float wi = (r1 * s1 - r0 * s0) * inv;
            *(uint_t*)(Wt + (size_t)m * KA + k * 32 + 2 * j) = pack_bf2(wr, wi);
        } else if (t < K_ * HN * M_ + K_ * M_) {
            int u = t - K_ * HN * M_;
            int m = u & 127, k = u >> 7;
            Wt[(size_t)m * KA + 1024 + k] = f2bf(D[k * M_ + m] * inv);
        }
    } else {
        // ---- xp projection ----
        int xb = bid - 273;                     // 0..511
        int b = xb >> 6;
        int tbase = (xb & 63) * 32;
        const float4* xsrc = (const float4*)(x + ((size_t)b * T_ + tbase) * D_);
        float4* xd = (float4*)xls;
        #pragma unroll
        for (int e = 0; e < 4; ++e) xd[tid + 256 * e] = xsrc[tid + 256 * e];
        __syncthreads();
        int kk = tid & 31, rg = tid >> 5;       // rg 0..7
        float accv[4] = {0.f, 0.f, 0.f, 0.f};
        #pragma unroll 4
        for (int i = 0; i < D_; ++i) {
            float rv = R[i * K_ + kk];
            #pragma unroll
            for (int rr = 0; rr < 4; ++rr)
                accv[rr] += xls[(rg + 8 * rr) * D_ + i] * rv;
        }
        #pragma unroll
        for (int rr = 0; rr < 4; ++rr) {
            int tt = tbase + rg + 8 * rr;
            A2[(size_t)(tt * 8 + b) * KA + 1024 + kk] = f2bf(accv[rr]);
            size_t base = (size_t)(b * K_ + kk) * T_;
            if (tt < T_ - 1) xpT[base + tt + 1] = accv[rr];
            if (tt == 0)     xpT[base] = 0.f;
        }
    }
}

// ---------------------------------------------------------------------------
// K_SCAN: fused scan_ends + carries + scan_write for one (b,k) series.
// 256 blocks x 512 thr; thread = (c = tid>>4, j = tid&15).
//  1) stage series (2048 floats of xpT) in LDS via one float4 load/thread
//  2) pass-1: per-chunk end-state -> E in LDS
//  3) carry combine: 16 threads (j), sequential over c, in-place seeds in E
//  4) pass-2: seeded chunk scan, packed bf16 (Re,Im) stores to A2
// Arithmetic order identical to R11's 3-kernel path -> bit-identical output.
// ---------------------------------------------------------------------------
__global__ __launch_bounds__(512) void k_scan(const float* __restrict__ xpT,
                                              const float* __restrict__ ws,
                                              uint_t* __restrict__ A2u) {
    __shared__ float xls[T_];          // 8 KB
    __shared__ float Er[512], Ei[512]; // 4 KB  (E, then seeds, [c*16+j])

    int tid = threadIdx.x;
    int k = blockIdx.x & 31, b = blockIdx.x >> 5;
    int c = tid >> 4, j = tid & 15;
    int col = k * 16 + j;

    // 1) stage series
    ((float4*)xls)[tid] = ((const float4*)(xpT + (size_t)(b * K_ + k) * T_))[tid];
    __syncthreads();

    float lr = ws[col], li = ws[512 + col];
    float br = ws[1024 + col], bi = ws[1536 + col];

    // 2) pass-1: chunk end-state
    {
        float sr = 0.f, si = 0.f;
        const float* xc = xls + c * CL;
        #pragma unroll 4
        for (int p = 0; p < CL; ++p) {
            float x1 = xc[p];
            float nr = br * x1 + lr * sr - li * si;
            float ni = bi * x1 + lr * si + li * sr;
            sr = nr; si = ni;
        }
        Er[c * 16 + j] = sr;
        Ei[c * 16 + j] = si;
    }
    __syncthreads();

    // 3) carry combine (16 threads), in-place: E[c] becomes the SEED of chunk c
    if (tid < 16) {
        float pr = lr, pi = li;            // lambda^64 via 6 squarings
        #pragma unroll
        for (int q = 0; q < 6; ++q) {
            float nr = pr * pr - pi * pi;
            float ni = 2.f * pr * pi;
            pr = nr; pi = ni;
        }
        float sr = 0.f, si = 0.f;
        for (int cc = 0; cc < CHK; ++cc) {
            int idx = cc * 16 + tid;
            float er = Er[idx], ei = Ei[idx];
            Er[idx] = sr; Ei[idx] = si;
            float nr = pr * sr - pi * si + er;
            float ni = pr * si + pi * sr + ei;
            sr = nr; si = ni;
        }
    }
    __syncthreads();

    // 4) pass-2: seeded scan, write A2
    {
        float sr = Er[c * 16 + j], si = Ei[c * 16 + j];
        int t0 = c * CL;
        const float* xc = xls + t0;
        uint_t* Ab = A2u + (size_t)(t0 * 8 + b) * (KA / 2) + col;
        #pragma unroll 4
        for (int p = 0; p < CL; ++p) {
            float x1 = xc[p];
            float nr = br * x1 + lr * sr - li * si;
            float ni = bi * x1 + lr * si + li * sr;
            sr = nr; si = ni;
            Ab[0] = pack_bf2(sr, si);
            Ab += 8 * (KA / 2);
        }
    }
}

// ---------------------------------------------------------------------------
// K5: bf16 MFMA GEMM (R11-identical). 512 blocks x 256 thr; block = 32 rows
// x 128 cols; wave: rh = wave&1 rows, chh = wave>>1 col-half, 4 accs.
// ---------------------------------------------------------------------------
__global__ __launch_bounds__(256, 2) void k_gemm(const ushort_t* __restrict__ A2,
                                                 const ushort_t* __restrict__ Wt,
                                                 const float* __restrict__ Do,
                                                 float* __restrict__ out) {
    int tid = threadIdx.x;
    int wave = tid >> 6;
    int rh = wave & 1;
    int chh = wave >> 1;
    int lane = tid & 63;
    int l16 = lane & 15;
    int quad = lane >> 4;
    int row0 = blockIdx.x * 32 + rh * 16;

    const ushort_t* Ap = A2 + (size_t)(row0 + l16) * KA + quad * 8;
    const ushort_t* Wp = Wt + (size_t)(chh * 64 + l16) * KA + quad * 8;

    floatx4 acc[4];
    #pragma unroll
    for (int n = 0; n < 4; ++n) acc[n] = (floatx4){0.f, 0.f, 0.f, 0.f};

    for (int g = 0; g < 11; ++g) {
        int k0 = g * 96;
        short8 a0 = *(const short8*)(Ap + k0);
        short8 a1 = *(const short8*)(Ap + k0 + 32);
        short8 a2 = *(const short8*)(Ap + k0 + 64);
        short8 bv[4][3];
        #pragma unroll
        for (int n = 0; n < 4; ++n) {
            #pragma unroll
            for (int s = 0; s < 3; ++s)
                bv[n][s] = *(const short8*)(Wp + (size_t)n * 16 * KA + k0 + s * 32);
        }
        #pragma unroll
        for (int n = 0; n < 4; ++n)
            acc[n] = __builtin_amdgcn_mfma_f32_16x16x32_bf16(a0, bv[n][0], acc[n], 0, 0, 0);
        #pragma unroll
        for (int n = 0; n < 4; ++n)
            acc[n] = __builtin_amdgcn_mfma_f32_16x16x32_bf16(a1, bv[n][1], acc[n], 0, 0, 0);
        #pragma unroll
        for (int n = 0; n < 4; ++n)
            acc[n] = __builtin_amdgcn_mfma_f32_16x16x32_bf16(a2, bv[n][2], acc[n], 0, 0, 0);
    }

    #pragma unroll
    for (int n = 0; n < 4; ++n) {
        int col = chh * 64 + n * 16 + l16;
        float dov = Do[col];
        #pragma unroll
        for (int q = 0; q < 4; ++q) {
            int r = row0 + quad * 4 + q;
            int b = r & 7, t = r >> 3;
            out[(size_t)(b * T_ + t) * M_ + col] = acc[n][q] + dov;
        }
    }
}

// ---------------------------------------------------------------------------
extern "C" void kernel_launch(void* const* d_in, const int* in_sizes, int n_in,
                              void* d_out, int out_size, void* d_ws, size_t ws_size,
                              hipStream_t stream) {
    const float* x     = (const float*)d_in[0];
    const float* R     = (const float*)d_in[1];
    const float* theta = (const float*)d_in[2];
    const float* lnC_r = (const float*)d_in[3];
    const float* lnC_i = (const float*)d_in[4];
    const float* D     = (const float*)d_in[5];
    const float* Do    = (const float*)d_in[6];
    float* out = (float*)d_out;

    float* wsf   = (float*)d_ws;
    float* lambp = wsf;                               // 2048 floats
    ushort_t* Wt = (ushort_t*)(wsf + 2048);           // 135168 ushorts = 67584 floats
    ushort_t* A2 = (ushort_t*)(wsf + 2048 + 67584);   // BT*KA ushorts = 8650752 floats
    float* xpT   = wsf + 2048 + 67584 + 8650752;      // 524288 floats

    k_pre<<<785, 256, 0, stream>>>(theta, lnC_r, lnC_i, D, x, R,
                                   lambp, Wt, xpT, A2);
    k_scan<<<256, 512, 0, stream>>>(xpT, lambp, (uint_t*)A2);
    k_gemm<<<512, 256, 0, stream>>>(A2, Wt, Do, out);
}